// Round 4
// baseline (452.730 us; speedup 1.0000x reference)
//
#include <hip/hip_runtime.h>

typedef _Float16 half8 __attribute__((ext_vector_type(8)));
typedef _Float16 half4 __attribute__((ext_vector_type(4)));
typedef float f32x4 __attribute__((ext_vector_type(4)));

#define T_STEPS 200
#define BATCH 256
#define D_IN 256
#define H1N 512
#define H2N 512
#define D_LAT 128
#define BHE (BATCH * H1N)   /* 131072 */
#define TC 50               /* timesteps per chunk */
#define NCH 4
#define MC (TC * BATCH)     /* 12800 rows per chunk */
#define SC_LO 4.8828125e-4f /* 2^-11 */

struct alignas(8) H4 { _Float16 v[4]; };
struct alignas(4) U4 { unsigned char v[4]; };

__device__ __forceinline__ void glds16(const void* g, void* l) {
    __builtin_amdgcn_global_load_lds(
        (const __attribute__((address_space(1))) unsigned int*)g,
        (__attribute__((address_space(3))) unsigned int*)l, 16, 0, 0);
}

// ============ GEMM2: C = S0 @ (W2h + 2^-11 W2l)^T + b2 ============
// BM=64, BN=128, BK=32, 512 thr (8 waves, 2x4), wave-tile 32x32.
// All staging via global_load_lds with pre-swizzled source (slot ^= (row>>1)&3).
__global__ __launch_bounds__(512, 4) void gemm2_k(const _Float16* __restrict__ A,
                                                  const _Float16* __restrict__ Bh,
                                                  const _Float16* __restrict__ Bl,
                                                  const float* __restrict__ bias,
                                                  float* __restrict__ C,
                                                  int M, int N, int K) {
    __shared__ _Float16 sA[2][64 * 32];
    __shared__ _Float16 sBh[2][128 * 32];
    __shared__ _Float16 sBl[2][128 * 32];

    const int tid = threadIdx.x, lane = tid & 63, wid = tid >> 6;
    const int m0 = blockIdx.x * 64, n0 = blockIdx.y * 128;
    const int wr = wid >> 2, wc = wid & 3;
    const int frow = lane & 15, kb = lane >> 4;
    const int srow16 = lane >> 2, sls = lane & 3;

    f32x4 acc0[2][2] = {};
    f32x4 acc1[2][2] = {};
    const int nk = K / 32;

    auto stage = [&](int ph, int k0) {
        for (int j = wid; j < 20; j += 8) {
            const _Float16* gb;
            _Float16* lb;
            int row0;
            if (j < 4)       { gb = A  + (size_t)m0 * K; lb = &sA[ph][0];  row0 = j * 16; }
            else if (j < 12) { gb = Bh + (size_t)n0 * K; lb = &sBh[ph][0]; row0 = (j - 4) * 16; }
            else             { gb = Bl + (size_t)n0 * K; lb = &sBl[ph][0]; row0 = (j - 12) * 16; }
            const int row = row0 + srow16;
            const int gs = sls ^ ((row >> 1) & 3);
            glds16(gb + (size_t)row * K + k0 + 8 * gs, lb + row0 * 32);
        }
    };

    stage(0, 0);
    __syncthreads();

    for (int kt = 0; kt < nk; ++kt) {
        const int ph = kt & 1;
        if (kt + 1 < nk) stage(ph ^ 1, (kt + 1) * 32);

        half8 bh[2], bl[2];
#pragma unroll
        for (int ni = 0; ni < 2; ++ni) {
            const int br = wc * 32 + ni * 16 + frow;
            const int off = br * 32 + 8 * (kb ^ ((br >> 1) & 3));
            bh[ni] = *reinterpret_cast<const half8*>(&sBh[ph][off]);
            bl[ni] = *reinterpret_cast<const half8*>(&sBl[ph][off]);
        }
#pragma unroll
        for (int mi = 0; mi < 2; ++mi) {
            const int ar = wr * 32 + mi * 16 + frow;
            half8 a = *reinterpret_cast<const half8*>(&sA[ph][ar * 32 + 8 * (kb ^ ((ar >> 1) & 3))]);
#pragma unroll
            for (int ni = 0; ni < 2; ++ni) {
                acc0[mi][ni] = __builtin_amdgcn_mfma_f32_16x16x32_f16(a, bh[ni], acc0[mi][ni], 0, 0, 0);
                acc1[mi][ni] = __builtin_amdgcn_mfma_f32_16x16x32_f16(a, bl[ni], acc1[mi][ni], 0, 0, 0);
            }
        }
        __syncthreads();
    }

#pragma unroll
    for (int mi = 0; mi < 2; ++mi)
#pragma unroll
        for (int ni = 0; ni < 2; ++ni) {
            const int col = n0 + wc * 32 + ni * 16 + frow;
            const float bb = bias[col];
#pragma unroll
            for (int r = 0; r < 4; ++r) {
                const int m = m0 + wr * 32 + mi * 16 + kb * 4 + r;
                C[(size_t)m * N + col] = acc0[mi][ni][r] + SC_LO * acc1[mi][ni][r] + bb;
            }
        }
}

// ============ GEMM1: C = X @ (W1h + 2^-11 W1l)^T + b1, split fused into A-staging ============
__global__ __launch_bounds__(512, 4) void gemm1_k(const float* __restrict__ X,
                                                  const _Float16* __restrict__ Bh,
                                                  const _Float16* __restrict__ Bl,
                                                  const float* __restrict__ bias,
                                                  float* __restrict__ C,
                                                  int M, int N, int K) {
    __shared__ _Float16 sAh[2][64 * 32];
    __shared__ _Float16 sAl[2][64 * 32];
    __shared__ _Float16 sBh[2][128 * 32];
    __shared__ _Float16 sBl[2][128 * 32];

    const int tid = threadIdx.x, lane = tid & 63, wid = tid >> 6;
    const int m0 = blockIdx.x * 64, n0 = blockIdx.y * 128;
    const int wr = wid >> 2, wc = wid & 3;
    const int frow = lane & 15, kb = lane >> 4;
    const int srow16 = lane >> 2, sls = lane & 3;
    const int arow = tid >> 3, aq = tid & 7;  // A staging: 64 rows x 8 float4

    f32x4 acc0[2][2] = {};
    f32x4 acc1[2][2] = {};
    const int nk = K / 32;

    auto stageB = [&](int ph, int k0) {
        for (int j = wid; j < 16; j += 8) {
            const _Float16* gb = (j < 8) ? Bh : Bl;
            _Float16* lb = (j < 8) ? &sBh[ph][0] : &sBl[ph][0];
            const int row0 = (j & 7) * 16;
            const int row = row0 + srow16;
            const int gs = sls ^ ((row >> 1) & 3);
            glds16(gb + (size_t)(n0 + row) * K + k0 + 8 * gs, lb + row0 * 32);
        }
    };
    auto stageA = [&](int ph, int k0) {
        float4 v = *reinterpret_cast<const float4*>(&X[(size_t)(m0 + arow) * K + k0 + aq * 4]);
        float vv[4] = {v.x, v.y, v.z, v.w};
        half4 h, l;
#pragma unroll
        for (int c = 0; c < 4; ++c) {
            _Float16 hh = (_Float16)vv[c];
            h[c] = hh;
            l[c] = (_Float16)((vv[c] - (float)hh) * 2048.0f);
        }
        const int off = arow * 32 + 8 * ((aq >> 1) ^ ((arow >> 1) & 3)) + 4 * (aq & 1);
        *reinterpret_cast<half4*>(&sAh[ph][off]) = h;
        *reinterpret_cast<half4*>(&sAl[ph][off]) = l;
    };

    stageB(0, 0);
    stageA(0, 0);
    __syncthreads();

    for (int kt = 0; kt < nk; ++kt) {
        const int ph = kt & 1;
        if (kt + 1 < nk) {
            stageB(ph ^ 1, (kt + 1) * 32);
            stageA(ph ^ 1, (kt + 1) * 32);
        }
        half8 bh[2], bl[2];
#pragma unroll
        for (int ni = 0; ni < 2; ++ni) {
            const int br = wc * 32 + ni * 16 + frow;
            const int off = br * 32 + 8 * (kb ^ ((br >> 1) & 3));
            bh[ni] = *reinterpret_cast<const half8*>(&sBh[ph][off]);
            bl[ni] = *reinterpret_cast<const half8*>(&sBl[ph][off]);
        }
#pragma unroll
        for (int mi = 0; mi < 2; ++mi) {
            const int ar = wr * 32 + mi * 16 + frow;
            const int aoff = ar * 32 + 8 * (kb ^ ((ar >> 1) & 3));
            half8 ah = *reinterpret_cast<const half8*>(&sAh[ph][aoff]);
            half8 al = *reinterpret_cast<const half8*>(&sAl[ph][aoff]);
#pragma unroll
            for (int ni = 0; ni < 2; ++ni) {
                acc0[mi][ni] = __builtin_amdgcn_mfma_f32_16x16x32_f16(ah, bh[ni], acc0[mi][ni], 0, 0, 0);
                acc1[mi][ni] = __builtin_amdgcn_mfma_f32_16x16x32_f16(ah, bl[ni], acc1[mi][ni], 0, 0, 0);
                acc1[mi][ni] = __builtin_amdgcn_mfma_f32_16x16x32_f16(al, bh[ni], acc1[mi][ni], 0, 0, 0);
            }
        }
        __syncthreads();
    }

#pragma unroll
    for (int mi = 0; mi < 2; ++mi)
#pragma unroll
        for (int ni = 0; ni < 2; ++ni) {
            const int col = n0 + wc * 32 + ni * 16 + frow;
            const float bb = bias[col];
#pragma unroll
            for (int r = 0; r < 4; ++r) {
                const int m = m0 + wr * 32 + mi * 16 + kb * 4 + r;
                C[(size_t)m * N + col] = acc0[mi][ni][r] + SC_LO * acc1[mi][ni][r] + bb;
            }
        }
}

// ============ LIF scan, 4 elems/thread, chunk-carried state ============
__global__ __launch_bounds__(128) void lif4(const float4* __restrict__ H,
                                            const float* __restrict__ beta_ptr,
                                            H4* __restrict__ S,
                                            float4* __restrict__ mst,
                                            float4* __restrict__ cst,
                                            float4* __restrict__ fr,
                                            U4* __restrict__ slast,
                                            int first, int last, int writeS, int writeLast) {
    const int idx = blockIdx.x * 128 + threadIdx.x;  // < 32768
    const float be = fminf(fmaxf(beta_ptr[0], 0.f), 1.f);
    float m[4], cnt[4], r[4];
    if (first) {
#pragma unroll
        for (int c = 0; c < 4; ++c) { m[c] = 0.f; cnt[c] = 0.f; r[c] = 0.f; }
    } else {
        float4 mv = mst[idx], cv = cst[idx];
        m[0] = mv.x; m[1] = mv.y; m[2] = mv.z; m[3] = mv.w;
        cnt[0] = cv.x; cnt[1] = cv.y; cnt[2] = cv.z; cnt[3] = cv.w;
#pragma unroll
        for (int c = 0; c < 4; ++c) r[c] = (m[c] > 1.0f) ? 1.f : 0.f;
    }
#pragma unroll 2
    for (int t = 0; t < TC; ++t) {
        float4 hv = H[(size_t)t * (BHE / 4) + idx];
        float h[4] = {hv.x, hv.y, hv.z, hv.w};
        H4 s;
#pragma unroll
        for (int c = 0; c < 4; ++c) {
            m[c] = be * m[c] + h[c] - r[c];
            const bool sp = m[c] > 1.0f;
            r[c] = sp ? 1.f : 0.f;
            cnt[c] += sp ? 1.f : 0.f;
            s.v[c] = (_Float16)r[c];
        }
        if (writeS) S[(size_t)t * (BHE / 4) + idx] = s;
    }
    if (last) {
        fr[idx] = make_float4(cnt[0] * (1.f / 200.f), cnt[1] * (1.f / 200.f),
                              cnt[2] * (1.f / 200.f), cnt[3] * (1.f / 200.f));
        if (writeLast) {
            U4 u;
#pragma unroll
            for (int c = 0; c < 4; ++c) u.v[c] = (r[c] > 0.5f) ? 1 : 0;
            slast[idx] = u;
        }
    } else {
        mst[idx] = make_float4(m[0], m[1], m[2], m[3]);
        cst[idx] = make_float4(cnt[0], cnt[1], cnt[2], cnt[3]);
    }
}

// ============ weight splits (W1 + W2 in one dispatch) ============
__global__ __launch_bounds__(256) void wsplit(const float* __restrict__ W1, const float* __restrict__ W2,
                                              _Float16* __restrict__ W1h, _Float16* __restrict__ W1l,
                                              _Float16* __restrict__ W2h, _Float16* __restrict__ W2l) {
    const int i = blockIdx.x * 256 + threadIdx.x;  // < 98304 float4s
    const float* src;
    _Float16 *dh, *dl;
    int k;
    if (i < 32768) { src = W1; dh = W1h; dl = W1l; k = i; }
    else           { src = W2; dh = W2h; dl = W2l; k = i - 32768; }
    float4 v = reinterpret_cast<const float4*>(src)[k];
    float vv[4] = {v.x, v.y, v.z, v.w};
    half4 h, l;
#pragma unroll
    for (int c = 0; c < 4; ++c) {
        _Float16 hh = (_Float16)vv[c];
        h[c] = hh;
        l[c] = (_Float16)((vv[c] - (float)hh) * 2048.0f);
    }
    reinterpret_cast<half4*>(dh)[k] = h;
    reinterpret_cast<half4*>(dl)[k] = l;
}

// ============ latent = LN(s_last @ Wout^T + bout) ============
__global__ __launch_bounds__(128) void latent_ln(const unsigned char* __restrict__ s_last,
                                                 const float* __restrict__ Wout,
                                                 const float* __restrict__ bout,
                                                 const float* __restrict__ gamma,
                                                 const float* __restrict__ lbeta,
                                                 float* __restrict__ out) {
    const int b = blockIdx.x;
    const int d = threadIdx.x;
    __shared__ float sv[H2N];
    for (int k = d; k < H2N; k += 128) sv[k] = (float)s_last[b * H2N + k];
    __syncthreads();

    float a = 0.f;
    const float* w = &Wout[(size_t)d * H2N];
#pragma unroll 8
    for (int k = 0; k < H2N; ++k) a = fmaf(sv[k], w[k], a);
    a += bout[d];

    __shared__ float red[128];
    red[d] = a;
    __syncthreads();
    for (int s = 64; s > 0; s >>= 1) {
        if (d < s) red[d] += red[d + s];
        __syncthreads();
    }
    const float mu = red[0] * (1.0f / 128.0f);
    __syncthreads();
    const float df = a - mu;
    red[d] = df * df;
    __syncthreads();
    for (int s = 64; s > 0; s >>= 1) {
        if (d < s) red[d] += red[d + s];
        __syncthreads();
    }
    const float var = red[0] * (1.0f / 128.0f);
    out[(size_t)b * D_LAT + d] = df * (1.0f / sqrtf(var + 1e-5f)) * gamma[d] + lbeta[d];
}

extern "C" void kernel_launch(void* const* d_in, const int* in_sizes, int n_in,
                              void* d_out, int out_size, void* d_ws, size_t ws_size,
                              hipStream_t stream) {
    const float* X     = (const float*)d_in[0];
    const float* W1    = (const float*)d_in[1];
    const float* b1    = (const float*)d_in[2];
    const float* beta0 = (const float*)d_in[3];
    const float* W2    = (const float*)d_in[4];
    const float* b2    = (const float*)d_in[5];
    const float* beta1 = (const float*)d_in[6];
    const float* Wout  = (const float*)d_in[7];
    const float* bout  = (const float*)d_in[8];
    const float* lng   = (const float*)d_in[9];
    const float* lnb   = (const float*)d_in[10];

    float* out    = (float*)d_out;
    float* latent = out;
    float* fr0    = out + BATCH * D_LAT;
    float* fr1    = fr0 + BATCH * H1N;

    char* p = (char*)d_ws;
    float*     H_c = (float*)p;              p += (size_t)MC * H1N * 4;   // 26.2 MB
    _Float16*  S0  = (_Float16*)p;           p += (size_t)MC * H1N * 2;   // 13.1 MB
    _Float16*  W1h = (_Float16*)p;           p += (size_t)H1N * D_IN * 2;
    _Float16*  W1l = (_Float16*)p;           p += (size_t)H1N * D_IN * 2;
    _Float16*  W2h = (_Float16*)p;           p += (size_t)H2N * H1N * 2;
    _Float16*  W2l = (_Float16*)p;           p += (size_t)H2N * H1N * 2;
    float*     m0s = (float*)p;              p += (size_t)BHE * 4;
    float*     c0s = (float*)p;              p += (size_t)BHE * 4;
    float*     m1s = (float*)p;              p += (size_t)BHE * 4;
    float*     c1s = (float*)p;              p += (size_t)BHE * 4;
    unsigned char* s1l = (unsigned char*)p;  p += (size_t)BHE;

    wsplit<<<dim3(384), 256, 0, stream>>>(W1, W2, W1h, W1l, W2h, W2l);

    for (int c = 0; c < NCH; ++c) {
        const float* Xc = X + (size_t)c * TC * BATCH * D_IN;
        const int first = (c == 0), last = (c == NCH - 1);
        gemm1_k<<<dim3(MC / 64, H1N / 128), 512, 0, stream>>>(
            Xc, W1h, W1l, b1, H_c, MC, H1N, D_IN);
        lif4<<<dim3(256), 128, 0, stream>>>(
            (const float4*)H_c, beta0, (H4*)S0, (float4*)m0s, (float4*)c0s,
            (float4*)fr0, nullptr, first, last, 1, 0);
        gemm2_k<<<dim3(MC / 64, H2N / 128), 512, 0, stream>>>(
            S0, W2h, W2l, b2, H_c, MC, H2N, H1N);
        lif4<<<dim3(256), 128, 0, stream>>>(
            (const float4*)H_c, beta1, nullptr, (float4*)m1s, (float4*)c1s,
            (float4*)fr1, (U4*)s1l, first, last, 0, 1);
    }
    latent_ln<<<dim3(BATCH), 128, 0, stream>>>(s1l, Wout, bout, lng, lnb, latent);
}

// Round 5
// 419.335 us; speedup vs baseline: 1.0796x; 1.0796x over previous
//
#include <hip/hip_runtime.h>

typedef _Float16 half8 __attribute__((ext_vector_type(8)));
typedef _Float16 half4v __attribute__((ext_vector_type(4)));
typedef float f32x4 __attribute__((ext_vector_type(4)));

#define BATCH 256
#define D_IN 256
#define H1N 512
#define H2N 512
#define D_LAT 128
#define MROWS 51200          /* T*B */
#define BHE 131072           /* B*H */
#define SC_LO 4.8828125e-4f  /* 2^-11 */

struct alignas(4) H2F { _Float16 v[2]; };
struct alignas(2) U2 { unsigned char v[2]; };

__device__ __forceinline__ void glds16(const _Float16* g, _Float16* l) {
    __builtin_amdgcn_global_load_lds(
        (const __attribute__((address_space(1))) unsigned int*)g,
        (__attribute__((address_space(3))) unsigned int*)l, 16, 0, 0);
}

// ---------- fp16 2-term split: x = hi + 2^-11 * lo'  ----------
__global__ __launch_bounds__(256) void splitk(const float* __restrict__ in,
                                              _Float16* __restrict__ hi,
                                              _Float16* __restrict__ lo, int n4) {
    int i = blockIdx.x * 256 + threadIdx.x;
    if (i >= n4) return;
    float4 v = reinterpret_cast<const float4*>(in)[i];
    float vv[4] = {v.x, v.y, v.z, v.w};
    half4v h, l;
#pragma unroll
    for (int c = 0; c < 4; ++c) {
        _Float16 hh = (_Float16)vv[c];
        h[c] = hh;
        l[c] = (_Float16)((vv[c] - (float)hh) * 2048.0f);
    }
    reinterpret_cast<half4v*>(hi)[i] = h;
    reinterpret_cast<half4v*>(lo)[i] = l;
}

// ================= GEMM1: C = (Xh + 2^-11 Xl) @ (W1h + 2^-11 W1l)^T + b1 =================
// tile 128x64, BK=32, 256 thr (4 waves 2x2, wave-tile 64x32), 2-phase glds pipeline.
// Swizzle (verified r3/r4): physical 16B slot = logical ^ ((row>>1)&3), applied on
// global source (pre-swizzle) and on ds_read address — glds dest stays linear.
__global__ __launch_bounds__(256) void gemm1_k(const _Float16* __restrict__ Ah,
                                               const _Float16* __restrict__ Al,
                                               const _Float16* __restrict__ Bh,
                                               const _Float16* __restrict__ Bl,
                                               const float* __restrict__ bias,
                                               float* __restrict__ C) {
    __shared__ _Float16 sAh[2][128 * 32];
    __shared__ _Float16 sAl[2][128 * 32];
    __shared__ _Float16 sBh[2][64 * 32];
    __shared__ _Float16 sBl[2][64 * 32];

    const int tid = threadIdx.x, lane = tid & 63, wid = tid >> 6;
    const int m0 = blockIdx.x * 128, n0 = blockIdx.y * 64;
    const int wr = wid >> 1, wc = wid & 1;
    const int frow = lane & 15, kb = lane >> 4;
    const int rl = lane >> 2;  // row within a 16-row chunk
    const int lane_off = rl * D_IN + 8 * ((lane & 3) ^ ((rl >> 1) & 3));

    f32x4 acc0[4][2] = {};
    f32x4 acc1[4][2] = {};

    auto stage = [&](int ph, int k0) {
#pragma unroll
        for (int i = 0; i < 6; ++i) {
            const int c = wid + 4 * i;  // 0..23, wave-uniform
            const _Float16* gp;
            _Float16* lp;
            if (c < 8)       { gp = Ah + (size_t)(m0 + c * 16) * D_IN;        lp = &sAh[ph][c * 16 * 32]; }
            else if (c < 16) { gp = Al + (size_t)(m0 + (c - 8) * 16) * D_IN;  lp = &sAl[ph][(c - 8) * 16 * 32]; }
            else if (c < 20) { gp = Bh + (size_t)(n0 + (c - 16) * 16) * D_IN; lp = &sBh[ph][(c - 16) * 16 * 32]; }
            else             { gp = Bl + (size_t)(n0 + (c - 20) * 16) * D_IN; lp = &sBl[ph][(c - 20) * 16 * 32]; }
            glds16(gp + k0 + lane_off, lp);
        }
    };

    stage(0, 0);
    __syncthreads();

    for (int kt = 0; kt < D_IN / 32; ++kt) {
        const int ph = kt & 1;
        if (kt < D_IN / 32 - 1) stage(ph ^ 1, (kt + 1) * 32);

        half8 bh[2], bl[2];
#pragma unroll
        for (int ni = 0; ni < 2; ++ni) {
            const int br = wc * 32 + ni * 16 + frow;
            const int off = br * 32 + 8 * (kb ^ ((br >> 1) & 3));
            bh[ni] = *reinterpret_cast<const half8*>(&sBh[ph][off]);
            bl[ni] = *reinterpret_cast<const half8*>(&sBl[ph][off]);
        }
#pragma unroll
        for (int mi = 0; mi < 4; ++mi) {
            const int ar = wr * 64 + mi * 16 + frow;
            const int aoff = ar * 32 + 8 * (kb ^ ((ar >> 1) & 3));
            half8 ah = *reinterpret_cast<const half8*>(&sAh[ph][aoff]);
            half8 al = *reinterpret_cast<const half8*>(&sAl[ph][aoff]);
#pragma unroll
            for (int ni = 0; ni < 2; ++ni) {
                acc0[mi][ni] = __builtin_amdgcn_mfma_f32_16x16x32_f16(ah, bh[ni], acc0[mi][ni], 0, 0, 0);
                acc1[mi][ni] = __builtin_amdgcn_mfma_f32_16x16x32_f16(ah, bl[ni], acc1[mi][ni], 0, 0, 0);
                acc1[mi][ni] = __builtin_amdgcn_mfma_f32_16x16x32_f16(al, bh[ni], acc1[mi][ni], 0, 0, 0);
            }
        }
        __syncthreads();
    }

#pragma unroll
    for (int mi = 0; mi < 4; ++mi)
#pragma unroll
        for (int ni = 0; ni < 2; ++ni) {
            const int col = n0 + wc * 32 + ni * 16 + frow;
            const float bb = bias[col];
#pragma unroll
            for (int r = 0; r < 4; ++r) {
                const int m = m0 + wr * 64 + mi * 16 + kb * 4 + r;
                C[(size_t)m * H1N + col] = acc0[mi][ni][r] + SC_LO * acc1[mi][ni][r] + bb;
            }
        }
}

// ================= GEMM2: C = S0 @ (W2h + 2^-11 W2l)^T + b2  (S0 exact fp16) =================
__global__ __launch_bounds__(256) void gemm2_k(const _Float16* __restrict__ A,
                                               const _Float16* __restrict__ Bh,
                                               const _Float16* __restrict__ Bl,
                                               const float* __restrict__ bias,
                                               float* __restrict__ C) {
    __shared__ _Float16 sA[2][128 * 32];
    __shared__ _Float16 sBh[2][64 * 32];
    __shared__ _Float16 sBl[2][64 * 32];

    const int tid = threadIdx.x, lane = tid & 63, wid = tid >> 6;
    const int m0 = blockIdx.x * 128, n0 = blockIdx.y * 64;
    const int wr = wid >> 1, wc = wid & 1;
    const int frow = lane & 15, kb = lane >> 4;
    const int rl = lane >> 2;
    const int lane_off = rl * H1N + 8 * ((lane & 3) ^ ((rl >> 1) & 3));

    f32x4 acc0[4][2] = {};
    f32x4 acc1[4][2] = {};

    auto stage = [&](int ph, int k0) {
#pragma unroll
        for (int i = 0; i < 4; ++i) {
            const int c = wid + 4 * i;  // 0..15
            const _Float16* gp;
            _Float16* lp;
            if (c < 8)       { gp = A  + (size_t)(m0 + c * 16) * H1N;         lp = &sA[ph][c * 16 * 32]; }
            else if (c < 12) { gp = Bh + (size_t)(n0 + (c - 8) * 16) * H1N;   lp = &sBh[ph][(c - 8) * 16 * 32]; }
            else             { gp = Bl + (size_t)(n0 + (c - 12) * 16) * H1N;  lp = &sBl[ph][(c - 12) * 16 * 32]; }
            glds16(gp + k0 + lane_off, lp);
        }
    };

    stage(0, 0);
    __syncthreads();

    for (int kt = 0; kt < H1N / 32; ++kt) {
        const int ph = kt & 1;
        if (kt < H1N / 32 - 1) stage(ph ^ 1, (kt + 1) * 32);

        half8 bh[2], bl[2];
#pragma unroll
        for (int ni = 0; ni < 2; ++ni) {
            const int br = wc * 32 + ni * 16 + frow;
            const int off = br * 32 + 8 * (kb ^ ((br >> 1) & 3));
            bh[ni] = *reinterpret_cast<const half8*>(&sBh[ph][off]);
            bl[ni] = *reinterpret_cast<const half8*>(&sBl[ph][off]);
        }
#pragma unroll
        for (int mi = 0; mi < 4; ++mi) {
            const int ar = wr * 64 + mi * 16 + frow;
            half8 a = *reinterpret_cast<const half8*>(&sA[ph][ar * 32 + 8 * (kb ^ ((ar >> 1) & 3))]);
#pragma unroll
            for (int ni = 0; ni < 2; ++ni) {
                acc0[mi][ni] = __builtin_amdgcn_mfma_f32_16x16x32_f16(a, bh[ni], acc0[mi][ni], 0, 0, 0);
                acc1[mi][ni] = __builtin_amdgcn_mfma_f32_16x16x32_f16(a, bl[ni], acc1[mi][ni], 0, 0, 0);
            }
        }
        __syncthreads();
    }

#pragma unroll
    for (int mi = 0; mi < 4; ++mi)
#pragma unroll
        for (int ni = 0; ni < 2; ++ni) {
            const int col = n0 + wc * 32 + ni * 16 + frow;
            const float bb = bias[col];
#pragma unroll
            for (int r = 0; r < 4; ++r) {
                const int m = m0 + wr * 64 + mi * 16 + kb * 4 + r;
                C[(size_t)m * H2N + col] = acc0[mi][ni][r] + SC_LO * acc1[mi][ni][r] + bb;
            }
        }
}

// ================= LIF scan over full T=200, 2 neurons/thread =================
__global__ __launch_bounds__(128) void lif2(const float2* __restrict__ H,
                                            const float* __restrict__ beta_ptr,
                                            H2F* __restrict__ S,
                                            float2* __restrict__ fr,
                                            U2* __restrict__ slast,
                                            int writeS, int writeLast) {
    const int idx = blockIdx.x * 128 + threadIdx.x;  // < 65536
    const float be = fminf(fmaxf(beta_ptr[0], 0.f), 1.f);
    float m0 = 0.f, m1 = 0.f, r0 = 0.f, r1 = 0.f, c0 = 0.f, c1 = 0.f;
#pragma unroll 8
    for (int t = 0; t < 200; ++t) {
        float2 hv = H[(size_t)t * (BHE / 2) + idx];
        m0 = be * m0 + hv.x - r0;
        r0 = (m0 > 1.0f) ? 1.f : 0.f;
        c0 += r0;
        m1 = be * m1 + hv.y - r1;
        r1 = (m1 > 1.0f) ? 1.f : 0.f;
        c1 += r1;
        if (writeS) {
            H2F sv;
            sv.v[0] = (_Float16)r0;
            sv.v[1] = (_Float16)r1;
            S[(size_t)t * (BHE / 2) + idx] = sv;
        }
    }
    fr[idx] = make_float2(c0 * (1.f / 200.f), c1 * (1.f / 200.f));
    if (writeLast) {
        U2 u;
        u.v[0] = (r0 > 0.5f) ? 1 : 0;
        u.v[1] = (r1 > 0.5f) ? 1 : 0;
        slast[idx] = u;
    }
}

// ================= latent = LN(s_last @ Wout^T + bout) =================
__global__ __launch_bounds__(128) void latent_ln(const unsigned char* __restrict__ s_last,
                                                 const float* __restrict__ Wout,
                                                 const float* __restrict__ bout,
                                                 const float* __restrict__ gamma,
                                                 const float* __restrict__ lbeta,
                                                 float* __restrict__ out) {
    const int b = blockIdx.x;
    const int d = threadIdx.x;
    __shared__ float sv[H2N];
    for (int k = d; k < H2N; k += 128) sv[k] = (float)s_last[b * H2N + k];
    __syncthreads();

    float a = 0.f;
    const float* w = &Wout[(size_t)d * H2N];
#pragma unroll 8
    for (int k = 0; k < H2N; ++k) a = fmaf(sv[k], w[k], a);
    a += bout[d];

    __shared__ float red[128];
    red[d] = a;
    __syncthreads();
    for (int s = 64; s > 0; s >>= 1) {
        if (d < s) red[d] += red[d + s];
        __syncthreads();
    }
    const float mu = red[0] * (1.0f / 128.0f);
    __syncthreads();
    const float df = a - mu;
    red[d] = df * df;
    __syncthreads();
    for (int s = 64; s > 0; s >>= 1) {
        if (d < s) red[d] += red[d + s];
        __syncthreads();
    }
    const float var = red[0] * (1.0f / 128.0f);
    out[(size_t)b * D_LAT + d] = df * (1.0f / sqrtf(var + 1e-5f)) * gamma[d] + lbeta[d];
}

extern "C" void kernel_launch(void* const* d_in, const int* in_sizes, int n_in,
                              void* d_out, int out_size, void* d_ws, size_t ws_size,
                              hipStream_t stream) {
    const float* X     = (const float*)d_in[0];
    const float* W1    = (const float*)d_in[1];
    const float* b1    = (const float*)d_in[2];
    const float* beta0 = (const float*)d_in[3];
    const float* W2    = (const float*)d_in[4];
    const float* b2    = (const float*)d_in[5];
    const float* beta1 = (const float*)d_in[6];
    const float* Wout  = (const float*)d_in[7];
    const float* bout  = (const float*)d_in[8];
    const float* lng   = (const float*)d_in[9];
    const float* lnb   = (const float*)d_in[10];

    float* out    = (float*)d_out;
    float* latent = out;
    float* fr0    = out + BATCH * D_LAT;
    float* fr1    = fr0 + BATCH * H1N;

    char* p = (char*)d_ws;
    float*     H   = (float*)p;              p += (size_t)MROWS * H1N * 4;   // 104.9 MB
    _Float16*  S0  = (_Float16*)p;           p += (size_t)MROWS * H1N * 2;   // 52.4 MB
    _Float16*  Xh  = (_Float16*)p;           p += (size_t)MROWS * D_IN * 2;  // 26.2 MB
    _Float16*  Xl  = (_Float16*)p;           p += (size_t)MROWS * D_IN * 2;  // 26.2 MB
    _Float16*  W1h = (_Float16*)p;           p += (size_t)H1N * D_IN * 2;
    _Float16*  W1l = (_Float16*)p;           p += (size_t)H1N * D_IN * 2;
    _Float16*  W2h = (_Float16*)p;           p += (size_t)H2N * H1N * 2;
    _Float16*  W2l = (_Float16*)p;           p += (size_t)H2N * H1N * 2;
    unsigned char* s1l = (unsigned char*)p;  p += (size_t)BHE;

    // splits: X (13.1M elems), W1, W2
    splitk<<<dim3(MROWS * D_IN / 4 / 256), 256, 0, stream>>>(X, Xh, Xl, MROWS * D_IN / 4);
    splitk<<<dim3(H1N * D_IN / 4 / 256), 256, 0, stream>>>(W1, W1h, W1l, H1N * D_IN / 4);
    splitk<<<dim3(H2N * H1N / 4 / 256), 256, 0, stream>>>(W2, W2h, W2l, H2N * H1N / 4);

    // layer 1
    gemm1_k<<<dim3(MROWS / 128, H1N / 64), 256, 0, stream>>>(Xh, Xl, W1h, W1l, b1, H);
    lif2<<<dim3(BHE / 2 / 128), 128, 0, stream>>>(
        (const float2*)H, beta0, (H2F*)S0, (float2*)fr0, nullptr, 1, 0);
    // layer 2
    gemm2_k<<<dim3(MROWS / 128, H2N / 64), 256, 0, stream>>>(S0, W2h, W2l, b2, H);
    lif2<<<dim3(BHE / 2 / 128), 128, 0, stream>>>(
        (const float2*)H, beta1, nullptr, (float2*)fr1, (U2*)s1l, 0, 1);
    // readout
    latent_ln<<<dim3(BATCH), 128, 0, stream>>>(s1l, Wout, bout, lng, lnb, latent);
}

// Round 6
// 383.344 us; speedup vs baseline: 1.1810x; 1.0939x over previous
//
#include <hip/hip_runtime.h>

typedef _Float16 half8 __attribute__((ext_vector_type(8)));
typedef _Float16 half4v __attribute__((ext_vector_type(4)));
typedef float f32x4 __attribute__((ext_vector_type(4)));

#define BATCH 256
#define D_IN 256
#define H1N 512
#define H2N 512
#define D_LAT 128
#define MROWS 51200          /* T*B */
#define BHE 131072           /* B*H */
#define SC_LO 4.8828125e-4f  /* 2^-11 */

__device__ __forceinline__ void glds16(const _Float16* g, _Float16* l) {
    __builtin_amdgcn_global_load_lds(
        (const __attribute__((address_space(1))) unsigned int*)g,
        (__attribute__((address_space(3))) unsigned int*)l, 16, 0, 0);
}

// ---------- fp16 2-term split: x = hi + 2^-11 * lo' ----------
__global__ __launch_bounds__(256) void splitk(const float* __restrict__ in,
                                              _Float16* __restrict__ hi,
                                              _Float16* __restrict__ lo, int n4) {
    int i = blockIdx.x * 256 + threadIdx.x;
    if (i >= n4) return;
    float4 v = reinterpret_cast<const float4*>(in)[i];
    float vv[4] = {v.x, v.y, v.z, v.w};
    half4v h, l;
#pragma unroll
    for (int c = 0; c < 4; ++c) {
        _Float16 hh = (_Float16)vv[c];
        h[c] = hh;
        l[c] = (_Float16)((vv[c] - (float)hh) * 2048.0f);
    }
    reinterpret_cast<half4v*>(hi)[i] = h;
    reinterpret_cast<half4v*>(lo)[i] = l;
}

// XCD-grouped block decode: same XCD sweeps all 8 n-tiles of its m-panels
// (A-panel stays L2-resident). Bijective: 3200 = 8 xcd * 400 j.
__device__ __forceinline__ void decode_mn(int d, int& m0, int& n0) {
    const int xcd = d & 7, j = d >> 3;      // j in [0,400)
    const int nt = j & 7, mloc = j >> 3;    // mloc in [0,50)
    m0 = (mloc * 8 + xcd) * 128;
    n0 = nt * 64;
}

// ================= GEMM1: C = (Xh + 2^-11 Xl) @ (W1h + 2^-11 W1l)^T + b1 =================
// tile 128x64, BK=32, 256 thr (4 waves 2x2, wave-tile 64x32), 2-phase glds pipeline.
// Swizzle (verified r3-r5): 16B slot = logical ^ ((row>>1)&3), pre-swizzled on the
// global source; glds dest linear; same XOR on ds_read.
__global__ __launch_bounds__(256) void gemm1_k(const _Float16* __restrict__ Ah,
                                               const _Float16* __restrict__ Al,
                                               const _Float16* __restrict__ Bh,
                                               const _Float16* __restrict__ Bl,
                                               const float* __restrict__ bias,
                                               float* __restrict__ C) {
    __shared__ _Float16 sAh[2][128 * 32];
    __shared__ _Float16 sAl[2][128 * 32];
    __shared__ _Float16 sBh[2][64 * 32];
    __shared__ _Float16 sBl[2][64 * 32];

    const int tid = threadIdx.x, lane = tid & 63, wid = tid >> 6;
    int m0, n0;
    decode_mn(blockIdx.x, m0, n0);
    const int wr = wid >> 1, wc = wid & 1;
    const int frow = lane & 15, kb = lane >> 4;
    const int rl = lane >> 2;  // row within a 16-row chunk
    const int lane_off = rl * D_IN + 8 * ((lane & 3) ^ ((rl >> 1) & 3));

    f32x4 acc0[4][2] = {};
    f32x4 acc1[4][2] = {};

    auto stage = [&](int ph, int k0) {
#pragma unroll
        for (int i = 0; i < 6; ++i) {
            const int c = wid + 4 * i;  // 0..23, wave-uniform
            const _Float16* gp;
            _Float16* lp;
            if (c < 8)       { gp = Ah + (size_t)(m0 + c * 16) * D_IN;        lp = &sAh[ph][c * 16 * 32]; }
            else if (c < 16) { gp = Al + (size_t)(m0 + (c - 8) * 16) * D_IN;  lp = &sAl[ph][(c - 8) * 16 * 32]; }
            else if (c < 20) { gp = Bh + (size_t)(n0 + (c - 16) * 16) * D_IN; lp = &sBh[ph][(c - 16) * 16 * 32]; }
            else             { gp = Bl + (size_t)(n0 + (c - 20) * 16) * D_IN; lp = &sBl[ph][(c - 20) * 16 * 32]; }
            glds16(gp + k0 + lane_off, lp);
        }
    };

    stage(0, 0);
    __syncthreads();

    for (int kt = 0; kt < D_IN / 32; ++kt) {
        const int ph = kt & 1;
        if (kt < D_IN / 32 - 1) stage(ph ^ 1, (kt + 1) * 32);

        half8 bh[2], bl[2];
#pragma unroll
        for (int ni = 0; ni < 2; ++ni) {
            const int br = wc * 32 + ni * 16 + frow;
            const int off = br * 32 + 8 * (kb ^ ((br >> 1) & 3));
            bh[ni] = *reinterpret_cast<const half8*>(&sBh[ph][off]);
            bl[ni] = *reinterpret_cast<const half8*>(&sBl[ph][off]);
        }
#pragma unroll
        for (int mi = 0; mi < 4; ++mi) {
            const int ar = wr * 64 + mi * 16 + frow;
            const int aoff = ar * 32 + 8 * (kb ^ ((ar >> 1) & 3));
            half8 ah = *reinterpret_cast<const half8*>(&sAh[ph][aoff]);
            half8 al = *reinterpret_cast<const half8*>(&sAl[ph][aoff]);
#pragma unroll
            for (int ni = 0; ni < 2; ++ni) {
                acc0[mi][ni] = __builtin_amdgcn_mfma_f32_16x16x32_f16(ah, bh[ni], acc0[mi][ni], 0, 0, 0);
                acc1[mi][ni] = __builtin_amdgcn_mfma_f32_16x16x32_f16(ah, bl[ni], acc1[mi][ni], 0, 0, 0);
                acc1[mi][ni] = __builtin_amdgcn_mfma_f32_16x16x32_f16(al, bh[ni], acc1[mi][ni], 0, 0, 0);
            }
        }
        __syncthreads();
    }

#pragma unroll
    for (int mi = 0; mi < 4; ++mi)
#pragma unroll
        for (int ni = 0; ni < 2; ++ni) {
            const int col = n0 + wc * 32 + ni * 16 + frow;
            const float bb = bias[col];
#pragma unroll
            for (int r = 0; r < 4; ++r) {
                const int m = m0 + wr * 64 + mi * 16 + kb * 4 + r;
                C[(size_t)m * H1N + col] = acc0[mi][ni][r] + SC_LO * acc1[mi][ni][r] + bb;
            }
        }
}

// ================= GEMM2: C = S0 @ (W2h + 2^-11 W2l)^T + b2  (S0 exact fp16) =================
__global__ __launch_bounds__(256) void gemm2_k(const _Float16* __restrict__ A,
                                               const _Float16* __restrict__ Bh,
                                               const _Float16* __restrict__ Bl,
                                               const float* __restrict__ bias,
                                               float* __restrict__ C) {
    __shared__ _Float16 sA[2][128 * 32];
    __shared__ _Float16 sBh[2][64 * 32];
    __shared__ _Float16 sBl[2][64 * 32];

    const int tid = threadIdx.x, lane = tid & 63, wid = tid >> 6;
    int m0, n0;
    decode_mn(blockIdx.x, m0, n0);
    const int wr = wid >> 1, wc = wid & 1;
    const int frow = lane & 15, kb = lane >> 4;
    const int rl = lane >> 2;
    const int lane_off = rl * H1N + 8 * ((lane & 3) ^ ((rl >> 1) & 3));

    f32x4 acc0[4][2] = {};
    f32x4 acc1[4][2] = {};

    auto stage = [&](int ph, int k0) {
#pragma unroll
        for (int i = 0; i < 4; ++i) {
            const int c = wid + 4 * i;  // 0..15
            const _Float16* gp;
            _Float16* lp;
            if (c < 8)       { gp = A  + (size_t)(m0 + c * 16) * H1N;         lp = &sA[ph][c * 16 * 32]; }
            else if (c < 12) { gp = Bh + (size_t)(n0 + (c - 8) * 16) * H1N;   lp = &sBh[ph][(c - 8) * 16 * 32]; }
            else             { gp = Bl + (size_t)(n0 + (c - 12) * 16) * H1N;  lp = &sBl[ph][(c - 12) * 16 * 32]; }
            glds16(gp + k0 + lane_off, lp);
        }
    };

    stage(0, 0);
    __syncthreads();

    for (int kt = 0; kt < H1N / 32; ++kt) {
        const int ph = kt & 1;
        if (kt < H1N / 32 - 1) stage(ph ^ 1, (kt + 1) * 32);

        half8 bh[2], bl[2];
#pragma unroll
        for (int ni = 0; ni < 2; ++ni) {
            const int br = wc * 32 + ni * 16 + frow;
            const int off = br * 32 + 8 * (kb ^ ((br >> 1) & 3));
            bh[ni] = *reinterpret_cast<const half8*>(&sBh[ph][off]);
            bl[ni] = *reinterpret_cast<const half8*>(&sBl[ph][off]);
        }
#pragma unroll
        for (int mi = 0; mi < 4; ++mi) {
            const int ar = wr * 64 + mi * 16 + frow;
            half8 a = *reinterpret_cast<const half8*>(&sA[ph][ar * 32 + 8 * (kb ^ ((ar >> 1) & 3))]);
#pragma unroll
            for (int ni = 0; ni < 2; ++ni) {
                acc0[mi][ni] = __builtin_amdgcn_mfma_f32_16x16x32_f16(a, bh[ni], acc0[mi][ni], 0, 0, 0);
                acc1[mi][ni] = __builtin_amdgcn_mfma_f32_16x16x32_f16(a, bl[ni], acc1[mi][ni], 0, 0, 0);
            }
        }
        __syncthreads();
    }

#pragma unroll
    for (int mi = 0; mi < 4; ++mi)
#pragma unroll
        for (int ni = 0; ni < 2; ++ni) {
            const int col = n0 + wc * 32 + ni * 16 + frow;
            const float bb = bias[col];
#pragma unroll
            for (int r = 0; r < 4; ++r) {
                const int m = m0 + wr * 64 + mi * 16 + kb * 4 + r;
                C[(size_t)m * H2N + col] = acc0[mi][ni][r] + SC_LO * acc1[mi][ni][r] + bb;
            }
        }
}

// ================= LIF scan over full T=200, 1 neuron/thread, deep unroll =================
__global__ __launch_bounds__(256) void lif1(const float* __restrict__ H,
                                            const float* __restrict__ beta_ptr,
                                            _Float16* __restrict__ S,
                                            float* __restrict__ fr,
                                            unsigned char* __restrict__ slast,
                                            int writeS, int writeLast) {
    const int idx = blockIdx.x * 256 + threadIdx.x;  // < BHE
    const float be = fminf(fmaxf(beta_ptr[0], 0.f), 1.f);
    float m = 0.f, r = 0.f, c = 0.f;
#pragma unroll 20
    for (int t = 0; t < 200; ++t) {
        const float h = H[(size_t)t * BHE + idx];
        m = be * m + h - r;
        r = (m > 1.0f) ? 1.f : 0.f;
        c += r;
        if (writeS) S[(size_t)t * BHE + idx] = (_Float16)r;
    }
    fr[idx] = c * (1.f / 200.f);
    if (writeLast) slast[idx] = (r > 0.5f) ? 1 : 0;
}

// ================= latent = LN(s_last @ Wout^T + bout) =================
__global__ __launch_bounds__(128) void latent_ln(const unsigned char* __restrict__ s_last,
                                                 const float* __restrict__ Wout,
                                                 const float* __restrict__ bout,
                                                 const float* __restrict__ gamma,
                                                 const float* __restrict__ lbeta,
                                                 float* __restrict__ out) {
    const int b = blockIdx.x;
    const int d = threadIdx.x;
    __shared__ float sv[H2N];
    for (int k = d; k < H2N; k += 128) sv[k] = (float)s_last[b * H2N + k];
    __syncthreads();

    float a = 0.f;
    const float* w = &Wout[(size_t)d * H2N];
#pragma unroll 8
    for (int k = 0; k < H2N; ++k) a = fmaf(sv[k], w[k], a);
    a += bout[d];

    __shared__ float red[128];
    red[d] = a;
    __syncthreads();
    for (int s = 64; s > 0; s >>= 1) {
        if (d < s) red[d] += red[d + s];
        __syncthreads();
    }
    const float mu = red[0] * (1.0f / 128.0f);
    __syncthreads();
    const float df = a - mu;
    red[d] = df * df;
    __syncthreads();
    for (int s = 64; s > 0; s >>= 1) {
        if (d < s) red[d] += red[d + s];
        __syncthreads();
    }
    const float var = red[0] * (1.0f / 128.0f);
    out[(size_t)b * D_LAT + d] = df * (1.0f / sqrtf(var + 1e-5f)) * gamma[d] + lbeta[d];
}

extern "C" void kernel_launch(void* const* d_in, const int* in_sizes, int n_in,
                              void* d_out, int out_size, void* d_ws, size_t ws_size,
                              hipStream_t stream) {
    const float* X     = (const float*)d_in[0];
    const float* W1    = (const float*)d_in[1];
    const float* b1    = (const float*)d_in[2];
    const float* beta0 = (const float*)d_in[3];
    const float* W2    = (const float*)d_in[4];
    const float* b2    = (const float*)d_in[5];
    const float* beta1 = (const float*)d_in[6];
    const float* Wout  = (const float*)d_in[7];
    const float* bout  = (const float*)d_in[8];
    const float* lng   = (const float*)d_in[9];
    const float* lnb   = (const float*)d_in[10];

    float* out    = (float*)d_out;
    float* latent = out;
    float* fr0    = out + BATCH * D_LAT;
    float* fr1    = fr0 + BATCH * H1N;

    char* p = (char*)d_ws;
    float*     H   = (float*)p;              p += (size_t)MROWS * H1N * 4;   // 104.9 MB
    _Float16*  S0  = (_Float16*)p;           p += (size_t)MROWS * H1N * 2;   // 52.4 MB
    _Float16*  Xh  = (_Float16*)p;           p += (size_t)MROWS * D_IN * 2;  // 26.2 MB
    _Float16*  Xl  = (_Float16*)p;           p += (size_t)MROWS * D_IN * 2;  // 26.2 MB
    _Float16*  W1h = (_Float16*)p;           p += (size_t)H1N * D_IN * 2;
    _Float16*  W1l = (_Float16*)p;           p += (size_t)H1N * D_IN * 2;
    _Float16*  W2h = (_Float16*)p;           p += (size_t)H2N * H1N * 2;
    _Float16*  W2l = (_Float16*)p;           p += (size_t)H2N * H1N * 2;
    unsigned char* s1l = (unsigned char*)p;  p += (size_t)BHE;

    // splits: X (13.1M elems), W1, W2
    splitk<<<dim3(MROWS * D_IN / 4 / 256), 256, 0, stream>>>(X, Xh, Xl, MROWS * D_IN / 4);
    splitk<<<dim3(H1N * D_IN / 4 / 256), 256, 0, stream>>>(W1, W1h, W1l, H1N * D_IN / 4);
    splitk<<<dim3(H2N * H1N / 4 / 256), 256, 0, stream>>>(W2, W2h, W2l, H2N * H1N / 4);

    // layer 1
    gemm1_k<<<dim3((MROWS / 128) * (H1N / 64)), 256, 0, stream>>>(Xh, Xl, W1h, W1l, b1, H);
    lif1<<<dim3(BHE / 256), 256, 0, stream>>>(H, beta0, S0, fr0, nullptr, 1, 0);
    // layer 2
    gemm2_k<<<dim3((MROWS / 128) * (H2N / 64)), 256, 0, stream>>>(S0, W2h, W2l, b2, H);
    lif1<<<dim3(BHE / 256), 256, 0, stream>>>(H, beta1, nullptr, fr1, s1l, 0, 1);
    // readout
    latent_ln<<<dim3(BATCH), 128, 0, stream>>>(s1l, Wout, bout, lng, lnb, latent);
}

// Round 7
// 382.577 us; speedup vs baseline: 1.1834x; 1.0020x over previous
//
#include <hip/hip_runtime.h>

typedef _Float16 half8 __attribute__((ext_vector_type(8)));
typedef _Float16 half4v __attribute__((ext_vector_type(4)));
typedef float f32x4 __attribute__((ext_vector_type(4)));

#define BATCH 256
#define D_IN 256
#define H1N 512
#define H2N 512
#define D_LAT 128
#define MROWS 51200          /* T*B */
#define BHE 131072           /* B*H */
#define SC_LO 4.8828125e-4f  /* 2^-11 */

__device__ __forceinline__ void glds16(const _Float16* g, _Float16* l) {
    __builtin_amdgcn_global_load_lds(
        (const __attribute__((address_space(1))) unsigned int*)g,
        (__attribute__((address_space(3))) unsigned int*)l, 16, 0, 0);
}

// ---------- fp16 2-term split: x = hi + 2^-11 * lo' ----------
__global__ __launch_bounds__(256) void splitk(const float* __restrict__ in,
                                              _Float16* __restrict__ hi,
                                              _Float16* __restrict__ lo, int n4) {
    int i = blockIdx.x * 256 + threadIdx.x;
    if (i >= n4) return;
    float4 v = reinterpret_cast<const float4*>(in)[i];
    float vv[4] = {v.x, v.y, v.z, v.w};
    half4v h, l;
#pragma unroll
    for (int c = 0; c < 4; ++c) {
        _Float16 hh = (_Float16)vv[c];
        h[c] = hh;
        l[c] = (_Float16)((vv[c] - (float)hh) * 2048.0f);
    }
    reinterpret_cast<half4v*>(hi)[i] = h;
    reinterpret_cast<half4v*>(lo)[i] = l;
}

// XCD-grouped decode for 1600 blocks (= 8 xcd * 200): same XCD sweeps the 4
// n-tiles of its m-panels -> A-panel L2-resident. Bijective (1600 % 8 == 0).
__device__ __forceinline__ void decode_mn(int d, int& m0, int& n0) {
    const int xcd = d & 7, j = d >> 3;      // j in [0,200)
    const int nt = j & 3, mloc = j >> 2;    // mloc in [0,50)
    m0 = (mloc * 8 + xcd) * 128;
    n0 = nt * 128;
}

// ================= GEMM1: C = (Xh + 2^-11 Xl) @ (W1h + 2^-11 W1l)^T + b1 =================
// tile 128x128, BK=32, 256 thr (4 waves 2x2, wave-tile 64x64), 2-phase glds pipeline.
// Swizzle (verified r3-r6): 16B slot = logical ^ ((row>>1)&3), pre-swizzled on the
// global source; glds dest linear; same XOR on ds_read.
__global__ __launch_bounds__(256, 2) void gemm1_k(const _Float16* __restrict__ Ah,
                                                  const _Float16* __restrict__ Al,
                                                  const _Float16* __restrict__ Bh,
                                                  const _Float16* __restrict__ Bl,
                                                  const float* __restrict__ bias,
                                                  float* __restrict__ C) {
    __shared__ _Float16 sAh[2][128 * 32];
    __shared__ _Float16 sAl[2][128 * 32];
    __shared__ _Float16 sBh[2][128 * 32];
    __shared__ _Float16 sBl[2][128 * 32];

    const int tid = threadIdx.x, lane = tid & 63, wid = tid >> 6;
    int m0, n0;
    decode_mn(blockIdx.x, m0, n0);
    const int wr = wid >> 1, wc = wid & 1;
    const int frow = lane & 15, kb = lane >> 4;
    const int rl = lane >> 2;  // row within a 16-row chunk
    const int lane_off = rl * D_IN + 8 * ((lane & 3) ^ ((rl >> 1) & 3));

    f32x4 acc0[4][4] = {};
    f32x4 acc1[4][4] = {};

    auto stage = [&](int ph, int k0) {
#pragma unroll
        for (int i = 0; i < 8; ++i) {
            const int c = wid + 4 * i;  // 0..31, wave-uniform
            const _Float16* gp;
            _Float16* lp;
            if (c < 8)       { gp = Ah + (size_t)(m0 + c * 16) * D_IN;        lp = &sAh[ph][c * 16 * 32]; }
            else if (c < 16) { gp = Al + (size_t)(m0 + (c - 8) * 16) * D_IN;  lp = &sAl[ph][(c - 8) * 16 * 32]; }
            else if (c < 24) { gp = Bh + (size_t)(n0 + (c - 16) * 16) * D_IN; lp = &sBh[ph][(c - 16) * 16 * 32]; }
            else             { gp = Bl + (size_t)(n0 + (c - 24) * 16) * D_IN; lp = &sBl[ph][(c - 24) * 16 * 32]; }
            glds16(gp + k0 + lane_off, lp);
        }
    };

    stage(0, 0);
    __syncthreads();

    for (int kt = 0; kt < D_IN / 32; ++kt) {
        const int ph = kt & 1;
        if (kt < D_IN / 32 - 1) stage(ph ^ 1, (kt + 1) * 32);

        half8 bh[4], bl[4];
#pragma unroll
        for (int ni = 0; ni < 4; ++ni) {
            const int br = wc * 64 + ni * 16 + frow;
            const int off = br * 32 + 8 * (kb ^ ((br >> 1) & 3));
            bh[ni] = *reinterpret_cast<const half8*>(&sBh[ph][off]);
            bl[ni] = *reinterpret_cast<const half8*>(&sBl[ph][off]);
        }
#pragma unroll
        for (int mi = 0; mi < 4; ++mi) {
            const int ar = wr * 64 + mi * 16 + frow;
            const int aoff = ar * 32 + 8 * (kb ^ ((ar >> 1) & 3));
            half8 ah = *reinterpret_cast<const half8*>(&sAh[ph][aoff]);
            half8 al = *reinterpret_cast<const half8*>(&sAl[ph][aoff]);
#pragma unroll
            for (int ni = 0; ni < 4; ++ni) {
                acc0[mi][ni] = __builtin_amdgcn_mfma_f32_16x16x32_f16(ah, bh[ni], acc0[mi][ni], 0, 0, 0);
                acc1[mi][ni] = __builtin_amdgcn_mfma_f32_16x16x32_f16(ah, bl[ni], acc1[mi][ni], 0, 0, 0);
                acc1[mi][ni] = __builtin_amdgcn_mfma_f32_16x16x32_f16(al, bh[ni], acc1[mi][ni], 0, 0, 0);
            }
        }
        __syncthreads();
    }

#pragma unroll
    for (int mi = 0; mi < 4; ++mi)
#pragma unroll
        for (int ni = 0; ni < 4; ++ni) {
            const int col = n0 + wc * 64 + ni * 16 + frow;
            const float bb = bias[col];
#pragma unroll
            for (int r = 0; r < 4; ++r) {
                const int m = m0 + wr * 64 + mi * 16 + kb * 4 + r;
                C[(size_t)m * H1N + col] = acc0[mi][ni][r] + SC_LO * acc1[mi][ni][r] + bb;
            }
        }
}

// ================= GEMM2: C = S0 @ (W2h + 2^-11 W2l)^T + b2  (S0 exact fp16) =================
__global__ __launch_bounds__(256, 2) void gemm2_k(const _Float16* __restrict__ A,
                                                  const _Float16* __restrict__ Bh,
                                                  const _Float16* __restrict__ Bl,
                                                  const float* __restrict__ bias,
                                                  float* __restrict__ C) {
    __shared__ _Float16 sA[2][128 * 32];
    __shared__ _Float16 sBh[2][128 * 32];
    __shared__ _Float16 sBl[2][128 * 32];

    const int tid = threadIdx.x, lane = tid & 63, wid = tid >> 6;
    int m0, n0;
    decode_mn(blockIdx.x, m0, n0);
    const int wr = wid >> 1, wc = wid & 1;
    const int frow = lane & 15, kb = lane >> 4;
    const int rl = lane >> 2;
    const int lane_off = rl * H1N + 8 * ((lane & 3) ^ ((rl >> 1) & 3));

    f32x4 acc0[4][4] = {};
    f32x4 acc1[4][4] = {};

    auto stage = [&](int ph, int k0) {
#pragma unroll
        for (int i = 0; i < 6; ++i) {
            const int c = wid + 4 * i;  // 0..23, wave-uniform
            const _Float16* gp;
            _Float16* lp;
            if (c < 8)       { gp = A  + (size_t)(m0 + c * 16) * H1N;         lp = &sA[ph][c * 16 * 32]; }
            else if (c < 16) { gp = Bh + (size_t)(n0 + (c - 8) * 16) * H1N;   lp = &sBh[ph][(c - 8) * 16 * 32]; }
            else             { gp = Bl + (size_t)(n0 + (c - 16) * 16) * H1N;  lp = &sBl[ph][(c - 16) * 16 * 32]; }
            glds16(gp + k0 + lane_off, lp);
        }
    };

    stage(0, 0);
    __syncthreads();

    for (int kt = 0; kt < H1N / 32; ++kt) {
        const int ph = kt & 1;
        if (kt < H1N / 32 - 1) stage(ph ^ 1, (kt + 1) * 32);

        half8 bh[4], bl[4];
#pragma unroll
        for (int ni = 0; ni < 4; ++ni) {
            const int br = wc * 64 + ni * 16 + frow;
            const int off = br * 32 + 8 * (kb ^ ((br >> 1) & 3));
            bh[ni] = *reinterpret_cast<const half8*>(&sBh[ph][off]);
            bl[ni] = *reinterpret_cast<const half8*>(&sBl[ph][off]);
        }
#pragma unroll
        for (int mi = 0; mi < 4; ++mi) {
            const int ar = wr * 64 + mi * 16 + frow;
            half8 a = *reinterpret_cast<const half8*>(&sA[ph][ar * 32 + 8 * (kb ^ ((ar >> 1) & 3))]);
#pragma unroll
            for (int ni = 0; ni < 4; ++ni) {
                acc0[mi][ni] = __builtin_amdgcn_mfma_f32_16x16x32_f16(a, bh[ni], acc0[mi][ni], 0, 0, 0);
                acc1[mi][ni] = __builtin_amdgcn_mfma_f32_16x16x32_f16(a, bl[ni], acc1[mi][ni], 0, 0, 0);
            }
        }
        __syncthreads();
    }

#pragma unroll
    for (int mi = 0; mi < 4; ++mi)
#pragma unroll
        for (int ni = 0; ni < 4; ++ni) {
            const int col = n0 + wc * 64 + ni * 16 + frow;
            const float bb = bias[col];
#pragma unroll
            for (int r = 0; r < 4; ++r) {
                const int m = m0 + wr * 64 + mi * 16 + kb * 4 + r;
                C[(size_t)m * H2N + col] = acc0[mi][ni][r] + SC_LO * acc1[mi][ni][r] + bb;
            }
        }
}

// ================= LIF scan over full T=200, 1 neuron/thread, deep unroll =================
__global__ __launch_bounds__(256) void lif1(const float* __restrict__ H,
                                            const float* __restrict__ beta_ptr,
                                            _Float16* __restrict__ S,
                                            float* __restrict__ fr,
                                            unsigned char* __restrict__ slast,
                                            int writeS, int writeLast) {
    const int idx = blockIdx.x * 256 + threadIdx.x;  // < BHE
    const float be = fminf(fmaxf(beta_ptr[0], 0.f), 1.f);
    float m = 0.f, r = 0.f, c = 0.f;
#pragma unroll 20
    for (int t = 0; t < 200; ++t) {
        const float h = H[(size_t)t * BHE + idx];
        m = be * m + h - r;
        r = (m > 1.0f) ? 1.f : 0.f;
        c += r;
        if (writeS) S[(size_t)t * BHE + idx] = (_Float16)r;
    }
    fr[idx] = c * (1.f / 200.f);
    if (writeLast) slast[idx] = (r > 0.5f) ? 1 : 0;
}

// ================= latent = LN(s_last @ Wout^T + bout) =================
__global__ __launch_bounds__(128) void latent_ln(const unsigned char* __restrict__ s_last,
                                                 const float* __restrict__ Wout,
                                                 const float* __restrict__ bout,
                                                 const float* __restrict__ gamma,
                                                 const float* __restrict__ lbeta,
                                                 float* __restrict__ out) {
    const int b = blockIdx.x;
    const int d = threadIdx.x;
    __shared__ float sv[H2N];
    for (int k = d; k < H2N; k += 128) sv[k] = (float)s_last[b * H2N + k];
    __syncthreads();

    float a = 0.f;
    const float* w = &Wout[(size_t)d * H2N];
#pragma unroll 8
    for (int k = 0; k < H2N; ++k) a = fmaf(sv[k], w[k], a);
    a += bout[d];

    __shared__ float red[128];
    red[d] = a;
    __syncthreads();
    for (int s = 64; s > 0; s >>= 1) {
        if (d < s) red[d] += red[d + s];
        __syncthreads();
    }
    const float mu = red[0] * (1.0f / 128.0f);
    __syncthreads();
    const float df = a - mu;
    red[d] = df * df;
    __syncthreads();
    for (int s = 64; s > 0; s >>= 1) {
        if (d < s) red[d] += red[d + s];
        __syncthreads();
    }
    const float var = red[0] * (1.0f / 128.0f);
    out[(size_t)b * D_LAT + d] = df * (1.0f / sqrtf(var + 1e-5f)) * gamma[d] + lbeta[d];
}

extern "C" void kernel_launch(void* const* d_in, const int* in_sizes, int n_in,
                              void* d_out, int out_size, void* d_ws, size_t ws_size,
                              hipStream_t stream) {
    const float* X     = (const float*)d_in[0];
    const float* W1    = (const float*)d_in[1];
    const float* b1    = (const float*)d_in[2];
    const float* beta0 = (const float*)d_in[3];
    const float* W2    = (const float*)d_in[4];
    const float* b2    = (const float*)d_in[5];
    const float* beta1 = (const float*)d_in[6];
    const float* Wout  = (const float*)d_in[7];
    const float* bout  = (const float*)d_in[8];
    const float* lng   = (const float*)d_in[9];
    const float* lnb   = (const float*)d_in[10];

    float* out    = (float*)d_out;
    float* latent = out;
    float* fr0    = out + BATCH * D_LAT;
    float* fr1    = fr0 + BATCH * H1N;

    char* p = (char*)d_ws;
    float*     H   = (float*)p;              p += (size_t)MROWS * H1N * 4;   // 104.9 MB
    _Float16*  S0  = (_Float16*)p;           p += (size_t)MROWS * H1N * 2;   // 52.4 MB
    _Float16*  Xh  = (_Float16*)p;           p += (size_t)MROWS * D_IN * 2;  // 26.2 MB
    _Float16*  Xl  = (_Float16*)p;           p += (size_t)MROWS * D_IN * 2;  // 26.2 MB
    _Float16*  W1h = (_Float16*)p;           p += (size_t)H1N * D_IN * 2;
    _Float16*  W1l = (_Float16*)p;           p += (size_t)H1N * D_IN * 2;
    _Float16*  W2h = (_Float16*)p;           p += (size_t)H2N * H1N * 2;
    _Float16*  W2l = (_Float16*)p;           p += (size_t)H2N * H1N * 2;
    unsigned char* s1l = (unsigned char*)p;  p += (size_t)BHE;

    // splits: X (13.1M elems), W1, W2
    splitk<<<dim3(MROWS * D_IN / 4 / 256), 256, 0, stream>>>(X, Xh, Xl, MROWS * D_IN / 4);
    splitk<<<dim3(H1N * D_IN / 4 / 256), 256, 0, stream>>>(W1, W1h, W1l, H1N * D_IN / 4);
    splitk<<<dim3(H2N * H1N / 4 / 256), 256, 0, stream>>>(W2, W2h, W2l, H2N * H1N / 4);

    // layer 1
    gemm1_k<<<dim3((MROWS / 128) * (H1N / 128)), 256, 0, stream>>>(Xh, Xl, W1h, W1l, b1, H);
    lif1<<<dim3(BHE / 256), 256, 0, stream>>>(H, beta0, S0, fr0, nullptr, 1, 0);
    // layer 2
    gemm2_k<<<dim3((MROWS / 128) * (H2N / 128)), 256, 0, stream>>>(S0, W2h, W2l, b2, H);
    lif1<<<dim3(BHE / 256), 256, 0, stream>>>(H, beta1, nullptr, fr1, s1l, 0, 1);
    // readout
    latent_ln<<<dim3(BATCH), 128, 0, stream>>>(s1l, Wout, bout, lng, lnb, latent);
}

// Round 8
// 328.757 us; speedup vs baseline: 1.3771x; 1.1637x over previous
//
#include <hip/hip_runtime.h>

typedef _Float16 half8 __attribute__((ext_vector_type(8)));
typedef _Float16 half4v __attribute__((ext_vector_type(4)));
typedef float f32x4 __attribute__((ext_vector_type(4)));

#define BATCH 256
#define D_IN 256
#define H1N 512
#define H2N 512
#define D_LAT 128
#define MROWS 51200          /* T*B */
#define BHE 131072           /* B*H */
#define SC_LO 4.8828125e-4f  /* 2^-11 */

__device__ __forceinline__ void glds16(const _Float16* g, _Float16* l) {
    __builtin_amdgcn_global_load_lds(
        (const __attribute__((address_space(1))) unsigned int*)g,
        (__attribute__((address_space(3))) unsigned int*)l, 16, 0, 0);
}

// ---------- X -> A1' = [Xh | Xh*2^-11 | Xd], K=768 ----------
__global__ __launch_bounds__(256) void splitX(const float* __restrict__ X,
                                              _Float16* __restrict__ A1) {
    int i = blockIdx.x * 256 + threadIdx.x;  // < MROWS*64
    int m = i >> 6, kq = i & 63;
    float4 v = reinterpret_cast<const float4*>(X)[i];
    float vv[4] = {v.x, v.y, v.z, v.w};
    half4v h, hs, d;
#pragma unroll
    for (int c = 0; c < 4; ++c) {
        _Float16 hh = (_Float16)vv[c];
        h[c] = hh;
        hs[c] = (_Float16)((float)hh * SC_LO);      // exact except fp16-subnormal rounding (<=2^-25)
        d[c] = (_Float16)(vv[c] - (float)hh);       // residual, abs err <= 2^-24
    }
    size_t base = (size_t)m * 768 + kq * 4;
    *reinterpret_cast<half4v*>(&A1[base]) = h;
    *reinterpret_cast<half4v*>(&A1[base + 256]) = hs;
    *reinterpret_cast<half4v*>(&A1[base + 512]) = d;
}

// ---------- W1 -> B1' = [Wh ; Wl ; Wh], rows 512, K=768 ----------
__global__ __launch_bounds__(256) void splitW1(const float* __restrict__ W,
                                               _Float16* __restrict__ Bp) {
    int i = blockIdx.x * 256 + threadIdx.x;  // < 512*64
    int r = i >> 6, kq = i & 63;
    float4 v = reinterpret_cast<const float4*>(W)[i];
    float vv[4] = {v.x, v.y, v.z, v.w};
    half4v h, l;
#pragma unroll
    for (int c = 0; c < 4; ++c) {
        _Float16 hh = (_Float16)vv[c];
        h[c] = hh;
        l[c] = (_Float16)((vv[c] - (float)hh) * 2048.0f);
    }
    size_t base = (size_t)r * 768 + kq * 4;
    *reinterpret_cast<half4v*>(&Bp[base]) = h;
    *reinterpret_cast<half4v*>(&Bp[base + 256]) = l;
    *reinterpret_cast<half4v*>(&Bp[base + 512]) = h;
}

// ---------- W2 -> B2' = [Wh ; Wl], rows 512, K=1024 ----------
__global__ __launch_bounds__(256) void splitW2(const float* __restrict__ W,
                                               _Float16* __restrict__ Bp) {
    int i = blockIdx.x * 256 + threadIdx.x;  // < 512*128
    int r = i >> 7, kq = i & 127;
    float4 v = reinterpret_cast<const float4*>(W)[i];
    float vv[4] = {v.x, v.y, v.z, v.w};
    half4v h, l;
#pragma unroll
    for (int c = 0; c < 4; ++c) {
        _Float16 hh = (_Float16)vv[c];
        h[c] = hh;
        l[c] = (_Float16)((vv[c] - (float)hh) * 2048.0f);
    }
    size_t base = (size_t)r * 1024 + kq * 4;
    *reinterpret_cast<half4v*>(&Bp[base]) = h;
    *reinterpret_cast<half4v*>(&Bp[base + 512]) = l;
}

// ================= counted-vmcnt GEMM: C[M,512] = A'[M,K] @ B'[512,K]^T + bias =================
// BM=256, BN=128, BK=64, 512 thr (8 waves 4x2, wave-tile 64x64), single acc[4][4].
// 3 LDS buffers (144KB), depth-2 prefetch, vmcnt(6) once per K-tile (never 0 in loop),
// raw s_barrier, setprio around MFMA clusters. Swizzle: 16B slot ^= (row&7), applied on
// pre-swizzled global source (glds dest linear) and on ds_read address. row&7 is lane-pure
// for both staging (lr) and frag reads (frow&7) since chunk/frag row bases are mult. of 8/16.
template <int KT>  // K = KT*64 : gemm1 KT=12, gemm2 KT=16
__global__ __launch_bounds__(512, 1) void gemm8(const _Float16* __restrict__ A,
                                                const _Float16* __restrict__ B,
                                                const float* __restrict__ bias,
                                                float* __restrict__ C) {
    constexpr int K = KT * 64;
    __shared__ _Float16 sA[3][256 * 64];  // 32KB x3
    __shared__ _Float16 sB[3][128 * 64];  // 16KB x3

    const int tid = threadIdx.x, lane = tid & 63, wid = tid >> 6;
    // grid 800 = 8 xcd * 100; same-XCD blocks sweep all 4 n-tiles of an m-panel
    const int bid = blockIdx.x;
    const int xcd = bid & 7, j = bid >> 3;      // j in [0,100)
    const int nt = j & 3, mloc = j >> 2;        // mloc in [0,25)
    const int m0 = (mloc * 8 + xcd) * 256, n0 = nt * 128;

    const int wr = wid & 3, wc = wid >> 2;      // 4x2 wave grid
    const int frow = lane & 15, kb = lane >> 4;

    // staging lane constants: chunk = 8 rows x 64 k (1KB); lane writes LDS byte lane*16
    const int lr = lane >> 3, ls = lane & 7;
    const int sl = 8 * (ls ^ lr);               // pre-swizzled global k-slot (elems)

    const _Float16* ga0 = A + (size_t)(m0 + (wid)*8 + lr) * K + sl;
    const _Float16* ga1 = A + (size_t)(m0 + (wid + 8) * 8 + lr) * K + sl;
    const _Float16* ga2 = A + (size_t)(m0 + (wid + 16) * 8 + lr) * K + sl;
    const _Float16* ga3 = A + (size_t)(m0 + (wid + 24) * 8 + lr) * K + sl;
    const _Float16* gb0 = B + (size_t)(n0 + (wid)*8 + lr) * K + sl;
    const _Float16* gb1 = B + (size_t)(n0 + (wid + 8) * 8 + lr) * K + sl;
    const int da0 = wid * 512, da1 = (wid + 8) * 512, da2 = (wid + 16) * 512, da3 = (wid + 24) * 512;
    const int db0 = wid * 512, db1 = (wid + 8) * 512;

    // fragment read offsets
    const int f7 = frow & 7;
    const int sk0 = 8 * (kb ^ f7);
    const int sk1 = 8 * ((4 + kb) ^ f7);
    const int abase = (wr * 64 + frow) * 64;
    const int bbase = (wc * 64 + frow) * 64;

    f32x4 acc[4][4] = {};

    // prologue: stage tiles 0 and 1 (6 glds each)
    glds16(ga0, &sA[0][da0]); glds16(ga1, &sA[0][da1]); glds16(ga2, &sA[0][da2]);
    glds16(ga3, &sA[0][da3]); glds16(gb0, &sB[0][db0]); glds16(gb1, &sB[0][db1]);
    glds16(ga0 + 64, &sA[1][da0]); glds16(ga1 + 64, &sA[1][da1]); glds16(ga2 + 64, &sA[1][da2]);
    glds16(ga3 + 64, &sA[1][da3]); glds16(gb0 + 64, &sB[1][db0]); glds16(gb1 + 64, &sB[1][db1]);
    asm volatile("s_waitcnt vmcnt(6)" ::: "memory");  // tile0 complete; tile1 in flight
    __builtin_amdgcn_s_barrier();

#pragma unroll
    for (int t = 0; t < KT; ++t) {
        const int cur = t % 3, nx2 = (t + 2) % 3;
        const int ko = (t + 2) * 64;
        half8 av[4], bv[4];
        // ---------- phase 0 (kk=0) ----------
#pragma unroll
        for (int mi = 0; mi < 4; ++mi)
            av[mi] = *reinterpret_cast<const half8*>(&sA[cur][abase + mi * 1024 + sk0]);
#pragma unroll
        for (int ni = 0; ni < 4; ++ni)
            bv[ni] = *reinterpret_cast<const half8*>(&sB[cur][bbase + ni * 1024 + sk0]);
        if (t + 2 < KT) {
            glds16(ga0 + ko, &sA[nx2][da0]);
            glds16(ga1 + ko, &sA[nx2][da1]);
            glds16(ga2 + ko, &sA[nx2][da2]);
        }
        __builtin_amdgcn_s_barrier();
        __builtin_amdgcn_s_setprio(1);
#pragma unroll
        for (int mi = 0; mi < 4; ++mi)
#pragma unroll
            for (int ni = 0; ni < 4; ++ni)
                acc[mi][ni] = __builtin_amdgcn_mfma_f32_16x16x32_f16(av[mi], bv[ni], acc[mi][ni], 0, 0, 0);
        __builtin_amdgcn_s_setprio(0);
        __builtin_amdgcn_s_barrier();
        // ---------- phase 1 (kk=1) ----------
#pragma unroll
        for (int mi = 0; mi < 4; ++mi)
            av[mi] = *reinterpret_cast<const half8*>(&sA[cur][abase + mi * 1024 + sk1]);
#pragma unroll
        for (int ni = 0; ni < 4; ++ni)
            bv[ni] = *reinterpret_cast<const half8*>(&sB[cur][bbase + ni * 1024 + sk1]);
        if (t + 2 < KT) {
            glds16(ga3 + ko, &sA[nx2][da3]);
            glds16(gb0 + ko, &sB[nx2][db0]);
            glds16(gb1 + ko, &sB[nx2][db1]);
            asm volatile("s_waitcnt vmcnt(6)" ::: "memory");  // tile t+1 ready; t+2 in flight
        } else if (t + 1 < KT) {
            asm volatile("s_waitcnt vmcnt(0)" ::: "memory");  // tail drain
        }
        __builtin_amdgcn_s_barrier();
        __builtin_amdgcn_s_setprio(1);
#pragma unroll
        for (int mi = 0; mi < 4; ++mi)
#pragma unroll
            for (int ni = 0; ni < 4; ++ni)
                acc[mi][ni] = __builtin_amdgcn_mfma_f32_16x16x32_f16(av[mi], bv[ni], acc[mi][ni], 0, 0, 0);
        __builtin_amdgcn_s_setprio(0);
        __builtin_amdgcn_s_barrier();
    }

    // epilogue: bias + store (C/D layout: col=lane&15, row=(lane>>4)*4+reg — m89-verified)
#pragma unroll
    for (int mi = 0; mi < 4; ++mi)
#pragma unroll
        for (int ni = 0; ni < 4; ++ni) {
            const int col = n0 + wc * 64 + ni * 16 + frow;
            const float bb = bias[col];
#pragma unroll
            for (int r = 0; r < 4; ++r) {
                const int m = m0 + wr * 64 + mi * 16 + kb * 4 + r;
                C[(size_t)m * 512 + col] = acc[mi][ni][r] + bb;
            }
        }
}

// ================= LIF scan layer0: H -> S' = [S | S*2^-11] rows M, K=1024; fr0 =================
__global__ __launch_bounds__(256) void lif_s(const float* __restrict__ H,
                                             const float* __restrict__ beta_ptr,
                                             _Float16* __restrict__ Sp,
                                             float* __restrict__ fr) {
    const int idx = blockIdx.x * 256 + threadIdx.x;  // < BHE
    const int b = idx >> 9, n = idx & 511;
    const float be = fminf(fmaxf(beta_ptr[0], 0.f), 1.f);
    float m = 0.f, r = 0.f, c = 0.f;
#pragma unroll 8
    for (int t = 0; t < 200; ++t) {
        const float h = H[(size_t)t * BHE + idx];
        m = be * m + h - r;
        r = (m > 1.0f) ? 1.f : 0.f;
        c += r;
        const size_t row = (size_t)(t * 256 + b) * 1024;
        Sp[row + n] = (_Float16)r;
        Sp[row + 512 + n] = (_Float16)(r * SC_LO);  // exact: {0, 2^-11}
    }
    fr[idx] = c * (1.f / 200.f);
}

// ================= LIF scan layer1: H -> fr1, s_last =================
__global__ __launch_bounds__(256) void lif_f(const float* __restrict__ H,
                                             const float* __restrict__ beta_ptr,
                                             float* __restrict__ fr,
                                             unsigned char* __restrict__ slast) {
    const int idx = blockIdx.x * 256 + threadIdx.x;  // < BHE
    const float be = fminf(fmaxf(beta_ptr[0], 0.f), 1.f);
    float m = 0.f, r = 0.f, c = 0.f;
#pragma unroll 20
    for (int t = 0; t < 200; ++t) {
        const float h = H[(size_t)t * BHE + idx];
        m = be * m + h - r;
        r = (m > 1.0f) ? 1.f : 0.f;
        c += r;
    }
    fr[idx] = c * (1.f / 200.f);
    slast[idx] = (r > 0.5f) ? 1 : 0;
}

// ================= latent = LN(s_last @ Wout^T + bout) =================
__global__ __launch_bounds__(128) void latent_ln(const unsigned char* __restrict__ s_last,
                                                 const float* __restrict__ Wout,
                                                 const float* __restrict__ bout,
                                                 const float* __restrict__ gamma,
                                                 const float* __restrict__ lbeta,
                                                 float* __restrict__ out) {
    const int b = blockIdx.x;
    const int d = threadIdx.x;
    __shared__ float sv[H2N];
    for (int k = d; k < H2N; k += 128) sv[k] = (float)s_last[b * H2N + k];
    __syncthreads();

    float a = 0.f;
    const float* w = &Wout[(size_t)d * H2N];
#pragma unroll 8
    for (int k = 0; k < H2N; ++k) a = fmaf(sv[k], w[k], a);
    a += bout[d];

    __shared__ float red[128];
    red[d] = a;
    __syncthreads();
    for (int s = 64; s > 0; s >>= 1) {
        if (d < s) red[d] += red[d + s];
        __syncthreads();
    }
    const float mu = red[0] * (1.0f / 128.0f);
    __syncthreads();
    const float df = a - mu;
    red[d] = df * df;
    __syncthreads();
    for (int s = 64; s > 0; s >>= 1) {
        if (d < s) red[d] += red[d + s];
        __syncthreads();
    }
    const float var = red[0] * (1.0f / 128.0f);
    out[(size_t)b * D_LAT + d] = df * (1.0f / sqrtf(var + 1e-5f)) * gamma[d] + lbeta[d];
}

extern "C" void kernel_launch(void* const* d_in, const int* in_sizes, int n_in,
                              void* d_out, int out_size, void* d_ws, size_t ws_size,
                              hipStream_t stream) {
    const float* X     = (const float*)d_in[0];
    const float* W1    = (const float*)d_in[1];
    const float* b1    = (const float*)d_in[2];
    const float* beta0 = (const float*)d_in[3];
    const float* W2    = (const float*)d_in[4];
    const float* b2    = (const float*)d_in[5];
    const float* beta1 = (const float*)d_in[6];
    const float* Wout  = (const float*)d_in[7];
    const float* bout  = (const float*)d_in[8];
    const float* lng   = (const float*)d_in[9];
    const float* lnb   = (const float*)d_in[10];

    float* out    = (float*)d_out;
    float* latent = out;
    float* fr0    = out + BATCH * D_LAT;
    float* fr1    = fr0 + BATCH * H1N;

    char* p = (char*)d_ws;
    _Float16* Sp  = (_Float16*)p;            p += (size_t)MROWS * 1024 * 2;  // 104.9 MB (S' for gemm2)
    float*    H   = (float*)p;               p += (size_t)MROWS * 512 * 4;   // 104.9 MB
    _Float16* B1p = (_Float16*)p;            p += (size_t)512 * 768 * 2;     // 0.79 MB
    _Float16* B2p = (_Float16*)p;            p += (size_t)512 * 1024 * 2;    // 1.05 MB
    unsigned char* s1l = (unsigned char*)p;  p += (size_t)BHE;
    _Float16* A1p = Sp;  // A1' (78.6 MB) aliases S' region: dead before lif_s writes S'

    splitX<<<dim3(MROWS * 64 / 256), 256, 0, stream>>>(X, A1p);
    splitW1<<<dim3(512 * 64 / 256), 256, 0, stream>>>(W1, B1p);
    splitW2<<<dim3(512 * 128 / 256), 256, 0, stream>>>(W2, B2p);

    // layer 1: K=768
    gemm8<12><<<dim3(800), 512, 0, stream>>>(A1p, B1p, b1, H);
    lif_s<<<dim3(BHE / 256), 256, 0, stream>>>(H, beta0, Sp, fr0);
    // layer 2: K=1024
    gemm8<16><<<dim3(800), 512, 0, stream>>>(Sp, B2p, b2, H);
    lif_f<<<dim3(BHE / 256), 256, 0, stream>>>(H, beta1, fr1, s1l);
    // readout
    latent_ln<<<dim3(BATCH), 128, 0, stream>>>(s1l, Wout, bout, lng, lnb, latent);
}